// Round 12
// baseline (224.967 us; speedup 1.0000x reference)
//
#include <hip/hip_runtime.h>
#include <hip/hip_bf16.h>

// Sparse MoE: T=2048, D=1024, E=8 routed (H=768, top-2) + shared GatedMLP (1536 hidden).
// R18: fc2 tail-fix done right. R17's N-split balanced FLOPs but doubled shared
// A-staging (full-K panels per block) and overflowed residency (576>512) -> +7us.
// K-split instead: shared 1536 -> 2 x 768 halves (staging bytes unchanged, +2.1M
// atomicAdds), making ALL fc2 blocks uniform M128/N128/K768. BK 128->64 (32KB LDS,
// 4 blocks/CU, 1024 slots >= 576 grid = single round, no tail) -- fc1w's proven shape.
// convgate + fc1w byte-identical to R15 (213.9 best).
// Ledger: R8 dbuf ~neutral (BK64@4wave regress; BK64@8wave is fc1w-proven); R9 coop
// -2x; R10 XCD swizzle regress; R11 fp32-direct regress; R12 conv-rides-fc1 +2.4;
// R13 spin -70%; R14 fc1 8-wave -11.8; R15 fc2 8-wave -8.2; R16 runtime-idx spill
// -6x (rule #20); R17 N-split +7.7 (staging-bytes, not FLOPs, set block cost).

typedef short bf16x8 __attribute__((ext_vector_type(8)));
typedef float f32x4 __attribute__((ext_vector_type(4)));

__device__ __forceinline__ unsigned short f2b(float f) {
    __hip_bfloat16 h = __float2bfloat16(f);
    return *reinterpret_cast<unsigned short*>(&h);
}

__device__ __forceinline__ void ldst16(const unsigned short* g, unsigned short* l) {
    __builtin_amdgcn_global_load_lds(
        (const __attribute__((address_space(1))) unsigned int*)g,
        (__attribute__((address_space(3))) unsigned int*)l, 16, 0, 0);
}

__device__ __forceinline__ void cvt8(const float* s, unsigned short* d, int j) {
    const float4* sp = reinterpret_cast<const float4*>(s) + (size_t)j * 2;
    float4 v0 = sp[0], v1 = sp[1];
    union { unsigned short u[8]; uint4 v; } o;
    o.u[0]=f2b(v0.x); o.u[1]=f2b(v0.y); o.u[2]=f2b(v0.z); o.u[3]=f2b(v0.w);
    o.u[4]=f2b(v1.x); o.u[5]=f2b(v1.y); o.u[6]=f2b(v1.z); o.u[7]=f2b(v1.w);
    *(reinterpret_cast<uint4*>(d) + j) = o.v;
}

// ------- convgate: W1/Ws1 conversion (blocks 0..7679) + gate (blocks 7680..9727) -----
__global__ __launch_bounds__(256) void k_convgate(const float* __restrict__ x,
                                                  const float* __restrict__ gw,
                                                  const float* __restrict__ W1,
                                                  const float* __restrict__ Ws1,
                                                  unsigned short* __restrict__ xb,
                                                  unsigned short* __restrict__ W1b,
                                                  unsigned short* __restrict__ Ws1b,
                                                  int* __restrict__ tokslot,
                                                  float* __restrict__ wroute,
                                                  int* __restrict__ cnt,
                                                  float* __restrict__ out) {
    __shared__ float red[4][8];
    __shared__ float sc[8];
    const int b = blockIdx.x, tid = threadIdx.x;
    if (b < 7680) {
        int i = b * 256 + tid;
        if (i < 1572864)  cvt8(W1,  W1b,  i);            // 8x1536x1024/8 chunks
        else              cvt8(Ws1, Ws1b, i - 1572864);  // 2x1536x1024/8 chunks
        return;
    }
    // ---- gate: one token per block, fully coalesced ----
    const int t = b - 7680;
    const int lane = tid & 63, w = tid >> 6;

    float4 v = reinterpret_cast<const float4*>(x + (size_t)t * 1024)[tid];
    union { unsigned short u[4]; ushort4 v4; } o;
    o.u[0]=f2b(v.x); o.u[1]=f2b(v.y); o.u[2]=f2b(v.z); o.u[3]=f2b(v.w);
    reinterpret_cast<ushort4*>(xb + (size_t)t * 1024)[tid] = o.v4;

    float p[8];
    for (int e = 0; e < 8; e++) {
        float4 g = reinterpret_cast<const float4*>(gw + (size_t)e * 1024)[tid];
        p[e] = v.x*g.x + v.y*g.y + v.z*g.z + v.w*g.w;
    }
    for (int e = 0; e < 8; e++)
        for (int off = 32; off > 0; off >>= 1) p[e] += __shfl_down(p[e], off, 64);
    if (lane == 0)
        for (int e = 0; e < 8; e++) red[w][e] = p[e];
    __syncthreads();
    if (tid < 8) sc[tid] = red[0][tid] + red[1][tid] + red[2][tid] + red[3][tid];
    __syncthreads();
    if (tid == 0) {
        float m = sc[0];
        for (int e = 1; e < 8; e++) m = fmaxf(m, sc[e]);
        float ex[8], sum = 0.f;
        for (int e = 0; e < 8; e++) { ex[e] = expf(sc[e] - m); sum += ex[e]; }
        float inv = 1.f / sum;
        int i1 = 0;
        for (int e = 1; e < 8; e++) if (sc[e] > sc[i1]) i1 = e;
        int i2 = -1; float s2 = -1e30f;
        for (int e = 0; e < 8; e++) if (e != i1 && sc[e] > s2) { s2 = sc[e]; i2 = e; }
        int p1 = atomicAdd(&cnt[i1 * 16], 1);          // 64B-padded counters
        tokslot[i1 * 2048 + p1] = t; wroute[i1 * 2048 + p1] = ex[i1] * inv;
        int p2 = atomicAdd(&cnt[i2 * 16], 1);
        tokslot[i2 * 2048 + p2] = t; wroute[i2 * 2048 + p2] = ex[i2] * inv;
    }
    reinterpret_cast<float4*>(out + (size_t)t * 1024)[tid] = (float4){0.f, 0.f, 0.f, 0.f};
}

// ---------- fc1 (bids 0..431) + W2/Ws2 conversion (bids 432..2351), 512 threads ------
// fc1: M128 x N128 (y|g each 128 rows of Bs), BK=64, 8 waves, per-wave M64xN32.
// LDS 48KB: As[128x64]=16KB + Bs[256x64]=32KB. Grid fc1 = 72 mt-slots x 6 ht.
__global__ __launch_bounds__(512) void k_fc1w(const unsigned short* __restrict__ xb,
                                              const unsigned short* __restrict__ W1b,
                                              const unsigned short* __restrict__ Ws1b,
                                              const float* __restrict__ W2,
                                              const float* __restrict__ Ws2,
                                              unsigned short* __restrict__ W2b,
                                              unsigned short* __restrict__ Ws2b,
                                              const int* __restrict__ tokslot,
                                              const float* __restrict__ wroute,
                                              const int* __restrict__ cnt,
                                              unsigned short* __restrict__ act_r,
                                              unsigned short* __restrict__ acts) {
    __shared__ alignas(16) unsigned short As[128 * 64];   // 16KB
    __shared__ alignas(16) unsigned short Bs[256 * 64];   // 32KB: rows 0..127 y, 128..255 g
    const int tid = threadIdx.x;
    if (blockIdx.x >= 432) {
        int i = (blockIdx.x - 432) * 512 + tid;           // 1920 x 512 = 983040 chunks
        if (i < 786432)  cvt8(W2,  W2b,  i);              // 8x1024x768/8
        else             cvt8(Ws2, Ws2b, i - 786432);     // 1024x1536/8
        return;
    }
    const int lane = tid & 63, w = tid >> 6;              // 8 waves
    const int wr = w >> 2, wc = w & 3;                    // 2 M x 4 N
    const int mt = blockIdx.x / 6, ht = blockIdx.x % 6;

    int pre = 0, sel = -1, base = 0;
    for (int ee = 0; ee < 10; ee++) {
        int til = (ee < 8) ? ((cnt[ee * 16] + 127) >> 7) : 16;
        if (sel < 0 && mt < pre + til) { sel = ee; base = pre; }
        pre += til;
    }
    if (sel < 0) return;
    const int e = sel, m0 = (mt - base) * 128, h0 = ht * 128;
    const int Te = (e < 8) ? cnt[e * 16] : 2048;
    const unsigned short* Bp = (e < 8) ? (W1b + (size_t)e * 1536 * 1024)
                                       : (Ws1b + (size_t)(e - 8) * 768 * 1024);
    const int gOff = (e < 8) ? 768 : 1536;

    const int kc = tid & 7;
    int aoff[2], boff[4];
    for (int q = 0; q < 2; q++) {
        int row = q * 64 + (tid >> 3);                 // 0..127
        int idx = m0 + row;
        int tk = (e < 8) ? ((idx < Te) ? tokslot[e * 2048 + idx] : 0) : idx;
        aoff[q] = tk * 1024 + ((kc ^ (row & 7)) << 3);
    }
    for (int q = 0; q < 4; q++) {
        int row = q * 64 + (tid >> 3);                 // 0..255
        int grow = (row < 128) ? (h0 + row) : (gOff + h0 + row - 128);
        boff[q] = grow * 1024 + ((kc ^ (row & 7)) << 3);
    }

    f32x4 accy[4][2], accg[4][2];
    for (int i = 0; i < 4; i++)
        for (int j = 0; j < 2; j++) {
            accy[i][j] = (f32x4){0.f, 0.f, 0.f, 0.f};
            accg[i][j] = (f32x4){0.f, 0.f, 0.f, 0.f};
        }

    for (int k0 = 0; k0 < 1024; k0 += 64) {
        for (int q = 0; q < 2; q++)
            ldst16(xb + aoff[q] + k0, As + (q * 512 + tid) * 8);
        for (int q = 0; q < 4; q++)
            ldst16(Bp + boff[q] + k0, Bs + (q * 512 + tid) * 8);
        __syncthreads();
        for (int kh = 0; kh < 2; kh++) {
            const int cq = kh * 4 + (lane >> 4);
            bf16x8 a[4], by[2], bg[2];
            for (int i = 0; i < 4; i++) {
                int r = 64 * wr + 16 * i + (lane & 15);
                a[i] = *(const bf16x8*)&As[r * 64 + ((cq ^ (r & 7)) << 3)];
            }
            for (int j = 0; j < 2; j++) {
                int ry = 32 * wc + 16 * j + (lane & 15);   // 0..127
                by[j] = *(const bf16x8*)&Bs[ry * 64 + ((cq ^ (ry & 7)) << 3)];
                int rg = 128 + ry;
                bg[j] = *(const bf16x8*)&Bs[rg * 64 + ((cq ^ (rg & 7)) << 3)];
            }
            __builtin_amdgcn_s_setprio(1);
            for (int i = 0; i < 4; i++)
                for (int j = 0; j < 2; j++) {
                    accy[i][j] = __builtin_amdgcn_mfma_f32_16x16x32_bf16(a[i], by[j], accy[i][j], 0, 0, 0);
                    accg[i][j] = __builtin_amdgcn_mfma_f32_16x16x32_bf16(a[i], bg[j], accg[i][j], 0, 0, 0);
                }
            __builtin_amdgcn_s_setprio(0);
        }
        __syncthreads();
    }

    for (int i = 0; i < 4; i++)
        for (int r = 0; r < 4; r++) {
            int irow = m0 + 64 * wr + 16 * i + ((lane >> 4) << 2) + r;
            if (irow >= Te) continue;
            float sw = (e < 8) ? wroute[e * 2048 + irow] : 1.0f;
            unsigned short* dst = (e < 8)
                ? (act_r + ((size_t)e * 2048 + irow) * 768)
                : (acts + (size_t)irow * 1536 + (size_t)(e - 8) * 768);
            for (int j = 0; j < 2; j++) {
                float y = accy[i][j][r], g = accg[i][j][r];
                float sg = g / (1.0f + __expf(-g));
                int col = h0 + 32 * wc + 16 * j + (lane & 15);  // < 768
                dst[col] = f2b(sw * y * sg);
            }
        }
}

// ------- unified fc2: uniform blocks M128/N128/K768, BK=64, 512 thr, LDS 32KB --------
// Grid 576 = 256 shared (16 mt x 8 nt x 2 k-halves) + 320 routed (40 mt-slots x 8 nt).
// 4 blocks/CU -> 1024 slots >= 576: single round, no tail. atomicAdd into zeroed out.
__global__ __launch_bounds__(512) void k_fc2u(const unsigned short* __restrict__ act_r,
                                              const unsigned short* __restrict__ acts,
                                              const unsigned short* __restrict__ W2b,
                                              const unsigned short* __restrict__ Ws2b,
                                              const int* __restrict__ tokslot,
                                              const int* __restrict__ cnt,
                                              float* __restrict__ out) {
    __shared__ alignas(16) unsigned short As[128 * 64];   // 16KB
    __shared__ alignas(16) unsigned short Bs[128 * 64];   // 16KB
    const int tid = threadIdx.x, lane = tid & 63, w = tid >> 6;  // 8 waves
    const int wr = w >> 2, wc = w & 3;                    // 2 M x 4 N

    int e, m0, n0, Te, stride, koff;
    const unsigned short *Ab, *Bb;
    if (blockIdx.x < 256) {
        // shared pseudo-expert, K-split: ks half in {0,1}
        const int s = blockIdx.x;
        const int mt = s >> 4, nt = (s >> 1) & 7, ks = s & 1;
        e = 8; m0 = mt * 128; n0 = nt * 128; Te = 2048;
        stride = 1536; koff = ks * 768;
        Ab = acts; Bb = Ws2b;
    } else {
        const int fb = blockIdx.x - 256;
        int mt = fb >> 3;
        const int nt = fb & 7;
        int pre = 0, sel = -1, base = 0;
        for (int ee = 0; ee < 8; ee++) {
            int til = (cnt[ee * 16] + 127) >> 7;
            if (sel < 0 && mt < pre + til) { sel = ee; base = pre; }
            pre += til;
        }
        if (sel < 0) return;
        e = sel; m0 = (mt - base) * 128; n0 = nt * 128; Te = cnt[e * 16];
        stride = 768; koff = 0;
        Ab = act_r + (size_t)e * 2048 * 768;
        Bb = W2b + (size_t)e * 1024 * 768;
    }

    const int kc = tid & 7;
    int aoff[2], boff[2];
    #pragma unroll
    for (int q = 0; q < 2; q++) {
        int row = q * 64 + (tid >> 3);                 // 0..127
        aoff[q] = (m0 + row) * stride + koff + ((kc ^ (row & 7)) << 3);
        boff[q] = (n0 + row) * stride + koff + ((kc ^ (row & 7)) << 3);
    }

    f32x4 acc[4][2];
    #pragma unroll
    for (int i = 0; i < 4; i++)
        #pragma unroll
        for (int j = 0; j < 2; j++) acc[i][j] = (f32x4){0.f, 0.f, 0.f, 0.f};

    for (int k0 = 0; k0 < 768; k0 += 64) {
        #pragma unroll
        for (int q = 0; q < 2; q++) {
            ldst16(Ab + aoff[q] + k0, As + (q * 512 + tid) * 8);
            ldst16(Bb + boff[q] + k0, Bs + (q * 512 + tid) * 8);
        }
        __syncthreads();
        #pragma unroll
        for (int kh = 0; kh < 2; kh++) {
            const int cq = kh * 4 + (lane >> 4);
            bf16x8 a[4], b[2];
            #pragma unroll
            for (int i = 0; i < 4; i++) {
                int r = 64 * wr + 16 * i + (lane & 15);
                a[i] = *(const bf16x8*)&As[r * 64 + ((cq ^ (r & 7)) << 3)];
            }
            #pragma unroll
            for (int j = 0; j < 2; j++) {
                int rb = 32 * wc + 16 * j + (lane & 15);   // 0..127
                b[j] = *(const bf16x8*)&Bs[rb * 64 + ((cq ^ (rb & 7)) << 3)];
            }
            __builtin_amdgcn_s_setprio(1);
            #pragma unroll
            for (int i = 0; i < 4; i++)
                #pragma unroll
                for (int j = 0; j < 2; j++)
                    acc[i][j] = __builtin_amdgcn_mfma_f32_16x16x32_bf16(a[i], b[j], acc[i][j], 0, 0, 0);
            __builtin_amdgcn_s_setprio(0);
        }
        __syncthreads();
    }

    #pragma unroll
    for (int i = 0; i < 4; i++)
        #pragma unroll
        for (int r = 0; r < 4; r++) {
            int irow = m0 + 64 * wr + 16 * i + ((lane >> 4) << 2) + r;
            if (irow >= Te) continue;
            int t = (e < 8) ? tokslot[e * 2048 + irow] : irow;
            #pragma unroll
            for (int j = 0; j < 2; j++) {
                int col = n0 + 32 * wc + 16 * j + (lane & 15);  // < 1024
                atomicAdd(out + (size_t)t * 1024 + col, acc[i][j][r]);
            }
        }
}

extern "C" void kernel_launch(void* const* d_in, const int* in_sizes, int n_in,
                              void* d_out, int out_size, void* d_ws, size_t ws_size,
                              hipStream_t stream) {
    const float* x   = (const float*)d_in[0];
    const float* gw  = (const float*)d_in[1];
    const float* W1  = (const float*)d_in[2];
    const float* W2  = (const float*)d_in[3];
    const float* Ws1 = (const float*)d_in[4];
    const float* Ws2 = (const float*)d_in[5];
    float* out = (float*)d_out;

    char* ws = (char*)d_ws;
    unsigned short* xb    = (unsigned short*)(ws + 0);          //  4,194,304
    unsigned short* W1b   = (unsigned short*)(ws + 4194304);    // 25,165,824
    unsigned short* Ws1b  = (unsigned short*)(ws + 29360128);   //  6,291,456
    unsigned short* W2b   = (unsigned short*)(ws + 35651584);   // 12,582,912
    unsigned short* Ws2b  = (unsigned short*)(ws + 48234496);   //  3,145,728
    unsigned short* act_r = (unsigned short*)(ws + 51380224);   // 25,165,824 (8x2048x768)
    unsigned short* acts  = (unsigned short*)(ws + 76546048);   //  6,291,456 (2048x1536)
    int*            tokslot = (int*)(ws + 82837504);            //     65,536 (8x2048)
    float*          wroute  = (float*)(ws + 82903040);          //     65,536
    int*            cnt     = (int*)(ws + 82968576);            //        512 (8x16 ints)

    hipMemsetAsync(cnt, 0, 512, stream);
    k_convgate<<<9728, 256, 0, stream>>>(x, gw, W1, Ws1,
                                         xb, W1b, Ws1b,
                                         tokslot, wroute, cnt, out);
    k_fc1w<<<2352, 512, 0, stream>>>(xb, W1b, Ws1b, W2, Ws2, W2b, Ws2b,
                                     tokslot, wroute, cnt, act_r, acts);
    k_fc2u<<<576, 512, 0, stream>>>(act_r, acts, W2b, Ws2b, tokslot, cnt, out);
}

// Round 13
// 210.524 us; speedup vs baseline: 1.0686x; 1.0686x over previous
//
#include <hip/hip_runtime.h>
#include <hip/hip_bf16.h>

// Sparse MoE: T=2048, D=1024, E=8 routed (H=768, top-2) + shared GatedMLP (1536 hidden).
// R19: byte-identical revert to R15 (213.9us, best measured). R17 (N-split, 47.3us
// fc2) and R18 (K-split+BK64, 54.1us fc2) both regressed vs R15's fc2 (~40us).
// Design-space map: fc2 MFMA-per-barrier (32 at BK128) dominates occupancy; tile
// re-balancing cannot beat the pigeonhole floor (576 routed-equivalent units over
// 512 resident slots => one CU always carries 3 units => ~40us). fc1w is rider-
// balanced at 582 TF; convgate streaming at ~3.5 TB/s. kernel-sum ~124us + fixed
// ~90us harness gap = ~214us structural plateau for the 3-dispatch decomposition.
// Ledger: R8 dbuf ~neutral; R9 coop -2x; R10 XCD swizzle regress; R11 fp32-direct
// regress; R12 conv-rides-fc1 +2.4; R13 spin -70%; R14 fc1 8-wave -11.8; R15 fc2
// 8-wave -8.2; R16 runtime-idx spill -6x (rule #20); R17 N-split +7.7 (staging
// bytes set block cost); R18 BK64 +14 (MFMA/barrier dominates occupancy for fc2).

typedef short bf16x8 __attribute__((ext_vector_type(8)));
typedef float f32x4 __attribute__((ext_vector_type(4)));

__device__ __forceinline__ unsigned short f2b(float f) {
    __hip_bfloat16 h = __float2bfloat16(f);
    return *reinterpret_cast<unsigned short*>(&h);
}

__device__ __forceinline__ void ldst16(const unsigned short* g, unsigned short* l) {
    __builtin_amdgcn_global_load_lds(
        (const __attribute__((address_space(1))) unsigned int*)g,
        (__attribute__((address_space(3))) unsigned int*)l, 16, 0, 0);
}

__device__ __forceinline__ void cvt8(const float* s, unsigned short* d, int j) {
    const float4* sp = reinterpret_cast<const float4*>(s) + (size_t)j * 2;
    float4 v0 = sp[0], v1 = sp[1];
    union { unsigned short u[8]; uint4 v; } o;
    o.u[0]=f2b(v0.x); o.u[1]=f2b(v0.y); o.u[2]=f2b(v0.z); o.u[3]=f2b(v0.w);
    o.u[4]=f2b(v1.x); o.u[5]=f2b(v1.y); o.u[6]=f2b(v1.z); o.u[7]=f2b(v1.w);
    *(reinterpret_cast<uint4*>(d) + j) = o.v;
}

// ------- convgate: W1/Ws1 conversion (blocks 0..7679) + gate (blocks 7680..9727) -----
__global__ __launch_bounds__(256) void k_convgate(const float* __restrict__ x,
                                                  const float* __restrict__ gw,
                                                  const float* __restrict__ W1,
                                                  const float* __restrict__ Ws1,
                                                  unsigned short* __restrict__ xb,
                                                  unsigned short* __restrict__ W1b,
                                                  unsigned short* __restrict__ Ws1b,
                                                  int* __restrict__ tokslot,
                                                  float* __restrict__ wroute,
                                                  int* __restrict__ cnt,
                                                  float* __restrict__ out) {
    __shared__ float red[4][8];
    __shared__ float sc[8];
    const int b = blockIdx.x, tid = threadIdx.x;
    if (b < 7680) {
        int i = b * 256 + tid;
        if (i < 1572864)  cvt8(W1,  W1b,  i);            // 8x1536x1024/8 chunks
        else              cvt8(Ws1, Ws1b, i - 1572864);  // 2x1536x1024/8 chunks
        return;
    }
    // ---- gate: one token per block, fully coalesced ----
    const int t = b - 7680;
    const int lane = tid & 63, w = tid >> 6;

    float4 v = reinterpret_cast<const float4*>(x + (size_t)t * 1024)[tid];
    union { unsigned short u[4]; ushort4 v4; } o;
    o.u[0]=f2b(v.x); o.u[1]=f2b(v.y); o.u[2]=f2b(v.z); o.u[3]=f2b(v.w);
    reinterpret_cast<ushort4*>(xb + (size_t)t * 1024)[tid] = o.v4;

    float p[8];
    for (int e = 0; e < 8; e++) {
        float4 g = reinterpret_cast<const float4*>(gw + (size_t)e * 1024)[tid];
        p[e] = v.x*g.x + v.y*g.y + v.z*g.z + v.w*g.w;
    }
    for (int e = 0; e < 8; e++)
        for (int off = 32; off > 0; off >>= 1) p[e] += __shfl_down(p[e], off, 64);
    if (lane == 0)
        for (int e = 0; e < 8; e++) red[w][e] = p[e];
    __syncthreads();
    if (tid < 8) sc[tid] = red[0][tid] + red[1][tid] + red[2][tid] + red[3][tid];
    __syncthreads();
    if (tid == 0) {
        float m = sc[0];
        for (int e = 1; e < 8; e++) m = fmaxf(m, sc[e]);
        float ex[8], sum = 0.f;
        for (int e = 0; e < 8; e++) { ex[e] = expf(sc[e] - m); sum += ex[e]; }
        float inv = 1.f / sum;
        int i1 = 0;
        for (int e = 1; e < 8; e++) if (sc[e] > sc[i1]) i1 = e;
        int i2 = -1; float s2 = -1e30f;
        for (int e = 0; e < 8; e++) if (e != i1 && sc[e] > s2) { s2 = sc[e]; i2 = e; }
        int p1 = atomicAdd(&cnt[i1 * 16], 1);          // 64B-padded counters
        tokslot[i1 * 2048 + p1] = t; wroute[i1 * 2048 + p1] = ex[i1] * inv;
        int p2 = atomicAdd(&cnt[i2 * 16], 1);
        tokslot[i2 * 2048 + p2] = t; wroute[i2 * 2048 + p2] = ex[i2] * inv;
    }
    reinterpret_cast<float4*>(out + (size_t)t * 1024)[tid] = (float4){0.f, 0.f, 0.f, 0.f};
}

// ---------- fc1 (bids 0..431) + W2/Ws2 conversion (bids 432..2351), 512 threads ------
// fc1: M128 x N128 (y|g each 128 rows of Bs), BK=64, 8 waves, per-wave M64xN32.
// LDS 48KB: As[128x64]=16KB + Bs[256x64]=32KB. Grid fc1 = 72 mt-slots x 6 ht.
__global__ __launch_bounds__(512) void k_fc1w(const unsigned short* __restrict__ xb,
                                              const unsigned short* __restrict__ W1b,
                                              const unsigned short* __restrict__ Ws1b,
                                              const float* __restrict__ W2,
                                              const float* __restrict__ Ws2,
                                              unsigned short* __restrict__ W2b,
                                              unsigned short* __restrict__ Ws2b,
                                              const int* __restrict__ tokslot,
                                              const float* __restrict__ wroute,
                                              const int* __restrict__ cnt,
                                              unsigned short* __restrict__ act_r,
                                              unsigned short* __restrict__ acts) {
    __shared__ alignas(16) unsigned short As[128 * 64];   // 16KB
    __shared__ alignas(16) unsigned short Bs[256 * 64];   // 32KB: rows 0..127 y, 128..255 g
    const int tid = threadIdx.x;
    if (blockIdx.x >= 432) {
        int i = (blockIdx.x - 432) * 512 + tid;           // 1920 x 512 = 983040 chunks
        if (i < 786432)  cvt8(W2,  W2b,  i);              // 8x1024x768/8
        else             cvt8(Ws2, Ws2b, i - 786432);     // 1024x1536/8
        return;
    }
    const int lane = tid & 63, w = tid >> 6;              // 8 waves
    const int wr = w >> 2, wc = w & 3;                    // 2 M x 4 N
    const int mt = blockIdx.x / 6, ht = blockIdx.x % 6;

    int pre = 0, sel = -1, base = 0;
    for (int ee = 0; ee < 10; ee++) {
        int til = (ee < 8) ? ((cnt[ee * 16] + 127) >> 7) : 16;
        if (sel < 0 && mt < pre + til) { sel = ee; base = pre; }
        pre += til;
    }
    if (sel < 0) return;
    const int e = sel, m0 = (mt - base) * 128, h0 = ht * 128;
    const int Te = (e < 8) ? cnt[e * 16] : 2048;
    const unsigned short* Bp = (e < 8) ? (W1b + (size_t)e * 1536 * 1024)
                                       : (Ws1b + (size_t)(e - 8) * 768 * 1024);
    const int gOff = (e < 8) ? 768 : 1536;

    const int kc = tid & 7;
    int aoff[2], boff[4];
    for (int q = 0; q < 2; q++) {
        int row = q * 64 + (tid >> 3);                 // 0..127
        int idx = m0 + row;
        int tk = (e < 8) ? ((idx < Te) ? tokslot[e * 2048 + idx] : 0) : idx;
        aoff[q] = tk * 1024 + ((kc ^ (row & 7)) << 3);
    }
    for (int q = 0; q < 4; q++) {
        int row = q * 64 + (tid >> 3);                 // 0..255
        int grow = (row < 128) ? (h0 + row) : (gOff + h0 + row - 128);
        boff[q] = grow * 1024 + ((kc ^ (row & 7)) << 3);
    }

    f32x4 accy[4][2], accg[4][2];
    for (int i = 0; i < 4; i++)
        for (int j = 0; j < 2; j++) {
            accy[i][j] = (f32x4){0.f, 0.f, 0.f, 0.f};
            accg[i][j] = (f32x4){0.f, 0.f, 0.f, 0.f};
        }

    for (int k0 = 0; k0 < 1024; k0 += 64) {
        for (int q = 0; q < 2; q++)
            ldst16(xb + aoff[q] + k0, As + (q * 512 + tid) * 8);
        for (int q = 0; q < 4; q++)
            ldst16(Bp + boff[q] + k0, Bs + (q * 512 + tid) * 8);
        __syncthreads();
        for (int kh = 0; kh < 2; kh++) {
            const int cq = kh * 4 + (lane >> 4);
            bf16x8 a[4], by[2], bg[2];
            for (int i = 0; i < 4; i++) {
                int r = 64 * wr + 16 * i + (lane & 15);
                a[i] = *(const bf16x8*)&As[r * 64 + ((cq ^ (r & 7)) << 3)];
            }
            for (int j = 0; j < 2; j++) {
                int ry = 32 * wc + 16 * j + (lane & 15);   // 0..127
                by[j] = *(const bf16x8*)&Bs[ry * 64 + ((cq ^ (ry & 7)) << 3)];
                int rg = 128 + ry;
                bg[j] = *(const bf16x8*)&Bs[rg * 64 + ((cq ^ (rg & 7)) << 3)];
            }
            __builtin_amdgcn_s_setprio(1);
            for (int i = 0; i < 4; i++)
                for (int j = 0; j < 2; j++) {
                    accy[i][j] = __builtin_amdgcn_mfma_f32_16x16x32_bf16(a[i], by[j], accy[i][j], 0, 0, 0);
                    accg[i][j] = __builtin_amdgcn_mfma_f32_16x16x32_bf16(a[i], bg[j], accg[i][j], 0, 0, 0);
                }
            __builtin_amdgcn_s_setprio(0);
        }
        __syncthreads();
    }

    for (int i = 0; i < 4; i++)
        for (int r = 0; r < 4; r++) {
            int irow = m0 + 64 * wr + 16 * i + ((lane >> 4) << 2) + r;
            if (irow >= Te) continue;
            float sw = (e < 8) ? wroute[e * 2048 + irow] : 1.0f;
            unsigned short* dst = (e < 8)
                ? (act_r + ((size_t)e * 2048 + irow) * 768)
                : (acts + (size_t)irow * 1536 + (size_t)(e - 8) * 768);
            for (int j = 0; j < 2; j++) {
                float y = accy[i][j][r], g = accg[i][j][r];
                float sg = g / (1.0f + __expf(-g));
                int col = h0 + 32 * wc + 16 * j + (lane & 15);  // < 768
                dst[col] = f2b(sw * y * sg);
            }
        }
}

// ------- unified fc2: 512 threads, M128 x N128, BK=128, 8 waves, LDS 64KB ------------
// Grid 448 = 56 mt-slots x 8 nt. Shared-expert tiles (K=1536) ordered FIRST (LPT).
// atomicAdd into out (routed scattered tokens + shared overlap).
__global__ __launch_bounds__(512) void k_fc2u(const unsigned short* __restrict__ act_r,
                                              const unsigned short* __restrict__ acts,
                                              const unsigned short* __restrict__ W2b,
                                              const unsigned short* __restrict__ Ws2b,
                                              const int* __restrict__ tokslot,
                                              const int* __restrict__ cnt,
                                              float* __restrict__ out) {
    __shared__ alignas(16) unsigned short As[128 * 128];  // 32KB
    __shared__ alignas(16) unsigned short Bs[128 * 128];  // 32KB
    const int tid = threadIdx.x, lane = tid & 63, w = tid >> 6;  // 8 waves
    const int wr = w >> 2, wc = w & 3;                    // 2 M x 4 N
    const int mt = blockIdx.x >> 3, nt = blockIdx.x & 7;

    // LPT order: shared pseudo-expert (K=1536, 2x work) first, then routed 0..7.
    const int order[9] = {8, 0, 1, 2, 3, 4, 5, 6, 7};
    int pre = 0, sel = -1, base = 0;
    for (int oi = 0; oi < 9; oi++) {
        int ee = order[oi];
        int til = (ee < 8) ? ((cnt[ee * 16] + 127) >> 7) : 16;
        if (sel < 0 && mt < pre + til) { sel = ee; base = pre; }
        pre += til;
    }
    if (sel < 0) return;
    const int e = sel, m0 = (mt - base) * 128, n0 = nt * 128;
    int Te, astride, bstride, K;
    const unsigned short *Ab, *Bb;
    if (e < 8) {
        Te = cnt[e * 16]; K = 768; astride = 768; bstride = 768;
        Ab = act_r + (size_t)e * 2048 * 768;
        Bb = W2b + (size_t)e * 1024 * 768;
    } else {
        Te = 2048; K = 1536; astride = 1536; bstride = 1536;
        Ab = acts;
        Bb = Ws2b;
    }

    const int cp = tid & 15;
    int aoff[4], boff[4];
    for (int q = 0; q < 4; q++) {
        int row = q * 32 + (tid >> 4);                 // 0..127
        aoff[q] = (m0 + row) * astride + ((cp ^ (row & 15)) << 3);
        boff[q] = (n0 + row) * bstride + ((cp ^ (row & 15)) << 3);
    }

    f32x4 acc[4][2];
    for (int i = 0; i < 4; i++)
        for (int j = 0; j < 2; j++) acc[i][j] = (f32x4){0.f, 0.f, 0.f, 0.f};

    for (int k0 = 0; k0 < K; k0 += 128) {
        for (int q = 0; q < 4; q++) {
            ldst16(Ab + aoff[q] + k0, As + (q * 512 + tid) * 8);
            ldst16(Bb + boff[q] + k0, Bs + (q * 512 + tid) * 8);
        }
        __syncthreads();
        for (int kh = 0; kh < 4; kh++) {
            const int cq = kh * 4 + (lane >> 4);
            bf16x8 a[4], b[2];
            for (int i = 0; i < 4; i++) {
                int r = 64 * wr + 16 * i + (lane & 15);
                a[i] = *(const bf16x8*)&As[r * 128 + ((cq ^ (r & 15)) << 3)];
            }
            for (int j = 0; j < 2; j++) {
                int rb = 32 * wc + 16 * j + (lane & 15);   // 0..127
                b[j] = *(const bf16x8*)&Bs[rb * 128 + ((cq ^ (rb & 15)) << 3)];
            }
            __builtin_amdgcn_s_setprio(1);
            for (int i = 0; i < 4; i++)
                for (int j = 0; j < 2; j++)
                    acc[i][j] = __builtin_amdgcn_mfma_f32_16x16x32_bf16(a[i], b[j], acc[i][j], 0, 0, 0);
            __builtin_amdgcn_s_setprio(0);
        }
        __syncthreads();
    }

    for (int i = 0; i < 4; i++)
        for (int r = 0; r < 4; r++) {
            int irow = m0 + 64 * wr + 16 * i + ((lane >> 4) << 2) + r;
            if (irow >= Te) continue;
            int t = (e < 8) ? tokslot[e * 2048 + irow] : irow;
            for (int j = 0; j < 2; j++) {
                int col = n0 + 32 * wc + 16 * j + (lane & 15);  // < 1024
                atomicAdd(out + (size_t)t * 1024 + col, acc[i][j][r]);
            }
        }
}

extern "C" void kernel_launch(void* const* d_in, const int* in_sizes, int n_in,
                              void* d_out, int out_size, void* d_ws, size_t ws_size,
                              hipStream_t stream) {
    const float* x   = (const float*)d_in[0];
    const float* gw  = (const float*)d_in[1];
    const float* W1  = (const float*)d_in[2];
    const float* W2  = (const float*)d_in[3];
    const float* Ws1 = (const float*)d_in[4];
    const float* Ws2 = (const float*)d_in[5];
    float* out = (float*)d_out;

    char* ws = (char*)d_ws;
    unsigned short* xb    = (unsigned short*)(ws + 0);          //  4,194,304
    unsigned short* W1b   = (unsigned short*)(ws + 4194304);    // 25,165,824
    unsigned short* Ws1b  = (unsigned short*)(ws + 29360128);   //  6,291,456
    unsigned short* W2b   = (unsigned short*)(ws + 35651584);   // 12,582,912
    unsigned short* Ws2b  = (unsigned short*)(ws + 48234496);   //  3,145,728
    unsigned short* act_r = (unsigned short*)(ws + 51380224);   // 25,165,824 (8x2048x768)
    unsigned short* acts  = (unsigned short*)(ws + 76546048);   //  6,291,456 (2048x1536)
    int*            tokslot = (int*)(ws + 82837504);            //     65,536 (8x2048)
    float*          wroute  = (float*)(ws + 82903040);          //     65,536
    int*            cnt     = (int*)(ws + 82968576);            //        512 (8x16 ints)

    hipMemsetAsync(cnt, 0, 512, stream);
    k_convgate<<<9728, 256, 0, stream>>>(x, gw, W1, Ws1,
                                         xb, W1b, Ws1b,
                                         tokslot, wroute, cnt, out);
    k_fc1w<<<2352, 512, 0, stream>>>(xb, W1b, Ws1b, W2, Ws2, W2b, Ws2b,
                                     tokslot, wroute, cnt, act_r, acts);
    k_fc2u<<<448, 512, 0, stream>>>(act_r, acts, W2b, Ws2b, tokslot, cnt, out);
}